// Round 1
// baseline (290.731 us; speedup 1.0000x reference)
//
#include <hip/hip_runtime.h>
#include <stdint.h>

#define KQ    8      // queries per KNN block
#define CAP   512    // candidate capacity per query (expected ~54 survivors)
#define KNN_T 256
#define KNB   16     // neighbors

typedef short short8 __attribute__((ext_vector_type(8)));
typedef float floatx4 __attribute__((ext_vector_type(4)));

__device__ __forceinline__ unsigned short f2bf(float x) {
  union { float f; uint32_t u; } v; v.f = x;
  uint32_t u = v.u + 0x7FFFu + ((v.u >> 16) & 1u);   // round-to-nearest-even
  return (unsigned short)(u >> 16);
}

__device__ __forceinline__ float d2comp(float qx, float qy, float qz, float qq,
                                        float px, float py, float pz) {
  // same expansion as reference: |q|^2 + |p|^2 - 2 q.p
  float pp  = px * px + py * py + pz * pz;
  float dot = qx * px + qy * py + qz * pz;
  return qq + pp - 2.0f * dot;
}

// ---------------------------------------------------------------------------
// Kernel 0: transpose W_att [c][f] -> bf16 Wt [f][c] (one-time, tiny)
// ---------------------------------------------------------------------------
__global__ void prep_kernel(const float* __restrict__ W_att,
                            unsigned short* __restrict__ Wt) {
  int id = blockIdx.x * 256 + threadIdx.x;   // 0..16383
  int c = id >> 7, f = id & 127;
  Wt[f * 128 + c] = f2bf(W_att[id]);
}

// ---------------------------------------------------------------------------
// Kernel 1: exact KNN via threshold-select.
// tau = max over 16 group-mins is a valid upper bound on the 16th-smallest d2.
// ---------------------------------------------------------------------------
__global__ __launch_bounds__(KNN_T) void knn_kernel(
    const float* __restrict__ pos, const int* __restrict__ idx,
    int* __restrict__ nbr, int N, int M) {
  __shared__ unsigned long long cand[KQ][CAP];
  __shared__ float gmin[KQ][16];
  __shared__ float tau_s[KQ];
  __shared__ int   cnt[KQ];

  const int tid = threadIdx.x;
  const int q0  = blockIdx.x * KQ;

  float qx[KQ], qy[KQ], qz[KQ], qq[KQ];
#pragma unroll
  for (int qi = 0; qi < KQ; ++qi) {
    int m  = q0 + qi;
    int ii = (m < M) ? idx[m] : 0;
    float a = pos[ii * 3 + 0], b = pos[ii * 3 + 1], c = pos[ii * 3 + 2];
    qx[qi] = a; qy[qi] = b; qz[qi] = c; qq[qi] = a * a + b * b + c * c;
  }

  for (int s = tid; s < KQ * CAP; s += KNN_T)
    ((unsigned long long*)cand)[s] = ~0ull;
  if (tid < KQ) cnt[tid] = 0;

  // ---- pass 1: per-thread mins ----
  float tmin[KQ];
#pragma unroll
  for (int qi = 0; qi < KQ; ++qi) tmin[qi] = 3.4e38f;
  for (int j = tid; j < N; j += KNN_T) {
    float px = pos[3 * j], py = pos[3 * j + 1], pz = pos[3 * j + 2];
#pragma unroll
    for (int qi = 0; qi < KQ; ++qi) {
      float d2 = d2comp(qx[qi], qy[qi], qz[qi], qq[qi], px, py, pz);
      tmin[qi] = fminf(tmin[qi], d2);
    }
  }
  // 16-lane group mins -> 16 groups; tau = max of group mins
#pragma unroll
  for (int qi = 0; qi < KQ; ++qi) {
    float v = tmin[qi];
    v = fminf(v, __shfl_xor(v, 1));
    v = fminf(v, __shfl_xor(v, 2));
    v = fminf(v, __shfl_xor(v, 4));
    v = fminf(v, __shfl_xor(v, 8));
    if ((tid & 15) == 0) gmin[qi][tid >> 4] = v;
  }
  __syncthreads();
  if (tid < KQ) {
    float t = gmin[tid][0];
#pragma unroll
    for (int g = 1; g < 16; ++g) t = fmaxf(t, gmin[tid][g]);
    // tiny inflation: robustness against rounding between pass1/pass2
    tau_s[tid] = t + fabsf(t) * 1e-5f + 1e-12f;
  }
  __syncthreads();
  float tau[KQ];
#pragma unroll
  for (int qi = 0; qi < KQ; ++qi) tau[qi] = tau_s[qi];

  // ---- pass 2: collect survivors ----
  for (int j = tid; j < N; j += KNN_T) {
    float px = pos[3 * j], py = pos[3 * j + 1], pz = pos[3 * j + 2];
#pragma unroll
    for (int qi = 0; qi < KQ; ++qi) {
      float d2 = d2comp(qx[qi], qy[qi], qz[qi], qq[qi], px, py, pz);
      if (d2 <= tau[qi]) {
        union { float f; uint32_t u; } dv; dv.f = fmaxf(d2, 0.0f);
        unsigned long long pk =
            ((unsigned long long)dv.u << 32) | (uint32_t)j;
        int sl = atomicAdd(&cnt[qi], 1);
        if (sl < CAP) cand[qi][sl] = pk;
      }
    }
  }
  __syncthreads();

  // ---- pass 3: one wave per query extracts 16 smallest ----
  const int wv = tid >> 6, ln = tid & 63;
  for (int qi = wv; qi < KQ; qi += 4) {
    int m = q0 + qi;
    unsigned long long c[CAP / 64];
#pragma unroll
    for (int i = 0; i < CAP / 64; ++i) c[i] = cand[qi][i * 64 + ln];
#pragma unroll
    for (int r = 0; r < KNB; ++r) {
      unsigned long long mn = c[0];
#pragma unroll
      for (int i = 1; i < CAP / 64; ++i) mn = (c[i] < mn) ? c[i] : mn;
#pragma unroll
      for (int off = 1; off < 64; off <<= 1) {
        unsigned long long o = __shfl_xor(mn, off);
        mn = (o < mn) ? o : mn;
      }
      if (m < M && ln == 0) nbr[m * KNB + r] = (int)(uint32_t)mn;
#pragma unroll
      for (int i = 0; i < CAP / 64; ++i)
        if (c[i] == mn) c[i] = ~0ull;
    }
  }
}

// ---------------------------------------------------------------------------
// Kernel 2: per-query LocSE + bf16-MFMA attention matvec + softmax + mean.
// 1 wave per query. C-layout: col=lane&15, row=quad*4+reg (verified m89/m91).
// ---------------------------------------------------------------------------
__global__ __launch_bounds__(64) void mid_kernel(
    const float* __restrict__ x, const float* __restrict__ pos,
    const int* __restrict__ idx, const float* __restrict__ W_pos,
    const float* __restrict__ b_pos, const unsigned short* __restrict__ Wt,
    const float* __restrict__ b_att, const int* __restrict__ nbr,
    float* __restrict__ aggr, int M) {
  __shared__ float fijf[16][132];                       // +4 pad: conflict-free scattered reads
  __shared__ __align__(16) unsigned short fijb[16][136]; // +8 pad: b128 frag reads at bank floor
  __shared__ int nbr_s[16];

  const int lane = threadIdx.x;
  const int mq   = blockIdx.x;

  if (lane < 16) nbr_s[lane] = nbr[mq * 16 + lane];
  __syncthreads();

  float wp[10];
#pragma unroll
  for (int t = 0; t < 10; ++t) wp[t] = W_pos[t * 64 + lane];
  float bp = b_pos[lane];
  int iq = idx[mq];
  float qx = pos[iq * 3], qy = pos[iq * 3 + 1], qz = pos[iq * 3 + 2];

  for (int k = 0; k < 16; ++k) {
    int jn = nbr_s[k];
    float px = pos[jn * 3], py = pos[jn * 3 + 1], pz = pos[jn * 3 + 2];
    float vx = qx - px, vy = qy - py, vz = qz - pz;
    float dd = sqrtf(vx * vx + vy * vy + vz * vz);
    float r = bp;
    r += qx * wp[0] + qy * wp[1] + qz * wp[2];
    r += px * wp[3] + py * wp[4] + pz * wp[5];
    r += vx * wp[6] + vy * wp[7] + vz * wp[8];
    r += dd * wp[9];
    r = fmaxf(r, 0.0f);
    float xv = x[jn * 64 + lane];
    fijf[k][lane]      = xv;
    fijf[k][64 + lane] = r;
    fijb[k][lane]      = f2bf(xv);
    fijb[k][64 + lane] = f2bf(r);
  }
  __syncthreads();

  const int col = lane & 15, quad = lane >> 4;

  // A-frags: A[m=lane&15][c = cs*32 + quad*8 + j]
  short8 af[4];
#pragma unroll
  for (int cs = 0; cs < 4; ++cs)
    af[cs] = *(const short8*)&fijb[col][cs * 32 + quad * 8];

  floatx4 acc[8];
#pragma unroll
  for (int ft = 0; ft < 8; ++ft) {
    float bav = b_att[ft * 16 + col];
    floatx4 a; a[0] = bav; a[1] = bav; a[2] = bav; a[3] = bav;
#pragma unroll
    for (int cs = 0; cs < 4; ++cs) {
      short8 bfrag = *(const short8*)&Wt[(ft * 16 + col) * 128 + cs * 32 + quad * 8];
      a = __builtin_amdgcn_mfma_f32_16x16x32_bf16(af[cs], bfrag, a, 0, 0, 0);
    }
    acc[ft] = a;
  }

  // softmax over the 128 features per row (row = neighbor)
  float e[8][4], rowsum[4];
#pragma unroll
  for (int r = 0; r < 4; ++r) {
    float mx = acc[0][r];
#pragma unroll
    for (int ft = 1; ft < 8; ++ft) mx = fmaxf(mx, acc[ft][r]);
    mx = fmaxf(mx, __shfl_xor(mx, 1));
    mx = fmaxf(mx, __shfl_xor(mx, 2));
    mx = fmaxf(mx, __shfl_xor(mx, 4));
    mx = fmaxf(mx, __shfl_xor(mx, 8));
    float sm = 0.0f;
#pragma unroll
    for (int ft = 0; ft < 8; ++ft) {
      e[ft][r] = expf(acc[ft][r] - mx);
      sm += e[ft][r];
    }
    sm += __shfl_xor(sm, 1);
    sm += __shfl_xor(sm, 2);
    sm += __shfl_xor(sm, 4);
    sm += __shfl_xor(sm, 8);
    rowsum[r] = sm;
  }

  // aggr[f] = mean_k( s * fij ); reduce 4 rows in-lane, then cross-quad
#pragma unroll
  for (int ft = 0; ft < 8; ++ft) {
    float ap = 0.0f;
#pragma unroll
    for (int r = 0; r < 4; ++r) {
      float s = e[ft][r] / rowsum[r];
      ap += s * fijf[quad * 4 + r][ft * 16 + col];
    }
    ap += __shfl_xor(ap, 16);
    ap += __shfl_xor(ap, 32);
    if (quad == 0) aggr[mq * 128 + ft * 16 + col] = ap * (1.0f / 16.0f);
  }
}

// ---------------------------------------------------------------------------
// Kernel 3: out = relu(aggr @ W_glob + b_glob), f32 vector GEMM
// ---------------------------------------------------------------------------
__global__ __launch_bounds__(256) void out_kernel(
    const float* __restrict__ aggr, const float* __restrict__ W_glob,
    const float* __restrict__ b_glob, float* __restrict__ out, int M) {
  __shared__ float ag[16][128];
  const int tid   = threadIdx.x;
  const int mbase = blockIdx.x * 16;
  for (int s = tid; s < 16 * 128; s += 256) {
    int r = s >> 7, cc = s & 127;
    int m = mbase + r;
    ((float*)ag)[s] = (m < M) ? aggr[m * 128 + cc] : 0.0f;
  }
  __syncthreads();
  const int f = tid & 127, h = tid >> 7;
  float acc[8];
  float bg = b_glob[f];
#pragma unroll
  for (int i = 0; i < 8; ++i) acc[i] = bg;
  for (int c = 0; c < 128; c += 4) {
    float w0 = W_glob[(c + 0) * 128 + f];
    float w1 = W_glob[(c + 1) * 128 + f];
    float w2 = W_glob[(c + 2) * 128 + f];
    float w3 = W_glob[(c + 3) * 128 + f];
#pragma unroll
    for (int i = 0; i < 8; ++i) {
      const floatx4 a4 = *(const floatx4*)&ag[h * 8 + i][c];
      acc[i] += a4[0] * w0 + a4[1] * w1 + a4[2] * w2 + a4[3] * w3;
    }
  }
#pragma unroll
  for (int i = 0; i < 8; ++i) {
    int m = mbase + h * 8 + i;
    if (m < M) out[m * 128 + f] = fmaxf(acc[i], 0.0f);
  }
}

// ---------------------------------------------------------------------------
extern "C" void kernel_launch(void* const* d_in, const int* in_sizes, int n_in,
                              void* d_out, int out_size, void* d_ws,
                              size_t ws_size, hipStream_t stream) {
  const float* x      = (const float*)d_in[0];
  const float* pos    = (const float*)d_in[1];
  const int*   idx    = (const int*)d_in[2];
  const float* W_pos  = (const float*)d_in[3];
  const float* b_pos  = (const float*)d_in[4];
  const float* W_att  = (const float*)d_in[5];
  const float* b_att  = (const float*)d_in[6];
  const float* W_glob = (const float*)d_in[7];
  const float* b_glob = (const float*)d_in[8];
  float* out = (float*)d_out;

  const int N = in_sizes[1] / 3;
  const int M = in_sizes[2];

  char* ws = (char*)d_ws;
  int* nbr = (int*)ws;                                               // M*16 int
  size_t off1 = ((size_t)M * KNB * 4 + 255) & ~(size_t)255;
  unsigned short* Wt = (unsigned short*)(ws + off1);                 // 128*128 bf16
  size_t off2 = off1 + ((128 * 128 * 2 + 255) & ~255);
  float* aggr = (float*)(ws + off2);                                 // M*128 f32

  prep_kernel<<<64, 256, 0, stream>>>(W_att, Wt);
  knn_kernel<<<(M + KQ - 1) / KQ, KNN_T, 0, stream>>>(pos, idx, nbr, N, M);
  mid_kernel<<<M, 64, 0, stream>>>(x, pos, idx, W_pos, b_pos, Wt, b_att, nbr,
                                   aggr, M);
  out_kernel<<<(M + 15) / 16, 256, 0, stream>>>(aggr, W_glob, b_glob, out, M);
}

// Round 2
// 238.167 us; speedup vs baseline: 1.2207x; 1.2207x over previous
//
#include <hip/hip_runtime.h>
#include <stdint.h>

#define KQ    8      // queries per KNN block
#define CAP   512    // candidate capacity per query (expected ~54 survivors)
#define KNN_T 256
#define KNB   16     // neighbors

typedef short short8 __attribute__((ext_vector_type(8)));
typedef float floatx4 __attribute__((ext_vector_type(4)));

__device__ __forceinline__ unsigned short f2bf(float x) {
  union { float f; uint32_t u; } v; v.f = x;
  uint32_t u = v.u + 0x7FFFu + ((v.u >> 16) & 1u);   // round-to-nearest-even
  return (unsigned short)(u >> 16);
}

// ---------------------------------------------------------------------------
// Kernel 0: (a) transpose W_att -> bf16 Wt[f][c]; (b) pack pos -> float4
// {x,y,z,|p|^2} with +inf-pp sentinels up to Npad (uniform KNN trip count).
// ---------------------------------------------------------------------------
__global__ void prep_kernel(const float* __restrict__ W_att,
                            unsigned short* __restrict__ Wt,
                            const float* __restrict__ pos,
                            float4* __restrict__ pos4, int N, int Npad) {
  int id = blockIdx.x * 256 + threadIdx.x;
  if (id < 128 * 128) {
    int c = id >> 7, f = id & 127;
    Wt[f * 128 + c] = f2bf(W_att[id]);
  }
  if (id < Npad) {
    float x = 0.f, y = 0.f, z = 0.f, pp = 3.0e38f;
    if (id < N) {
      x = pos[3 * id]; y = pos[3 * id + 1]; z = pos[3 * id + 2];
      pp = x * x + y * y + z * z;
    }
    pos4[id] = make_float4(x, y, z, pp);
  }
}

// ---------------------------------------------------------------------------
// Kernel 1: exact KNN via threshold-select in t-space (t = pp - 2 q.p; the
// per-query qq is a row constant so top-k by t == top-k by d2). tau = max of
// 16 disjoint-group mins >= t_(16). Exact fp32 d2 arbitration on survivors.
// ---------------------------------------------------------------------------
__global__ __launch_bounds__(KNN_T) void knn_kernel(
    const float4* __restrict__ pos4, const int* __restrict__ idx,
    int* __restrict__ nbr, int Npad, int M) {
  __shared__ unsigned long long cand[KQ][CAP];
  __shared__ float gmin[KQ][16];
  __shared__ float tau_s[KQ];
  __shared__ int   cnt[KQ];

  const int tid = threadIdx.x;
  const int q0  = blockIdx.x * KQ;
  const int iters = Npad / KNN_T;   // uniform across block

  float qx[KQ], qy[KQ], qz[KQ];
#pragma unroll
  for (int qi = 0; qi < KQ; ++qi) {
    int m  = q0 + qi;
    int ii = (m < M) ? idx[m] : 0;
    float4 qp = pos4[ii];
    qx[qi] = qp.x; qy[qi] = qp.y; qz[qi] = qp.z;
  }

  for (int s = tid; s < KQ * CAP; s += KNN_T)
    ((unsigned long long*)cand)[s] = ~0ull;
  if (tid < KQ) cnt[tid] = 0;

  // ---- pass 1: per-thread t-mins, register-double-buffered point stream ----
  float tmin[KQ];
#pragma unroll
  for (int qi = 0; qi < KQ; ++qi) tmin[qi] = 3.4e38f;
  {
    float4 cur = pos4[tid];
    for (int it = 0; it < iters - 1; ++it) {
      float4 nxt = pos4[tid + (it + 1) * KNN_T];   // prefetch next point
#pragma unroll
      for (int qi = 0; qi < KQ; ++qi) {
        float dot = fmaf(qx[qi], cur.x, fmaf(qy[qi], cur.y, qz[qi] * cur.z));
        float t   = fmaf(-2.0f, dot, cur.w);
        tmin[qi]  = fminf(tmin[qi], t);
      }
      cur = nxt;
    }
#pragma unroll
    for (int qi = 0; qi < KQ; ++qi) {
      float dot = fmaf(qx[qi], cur.x, fmaf(qy[qi], cur.y, qz[qi] * cur.z));
      float t   = fmaf(-2.0f, dot, cur.w);
      tmin[qi]  = fminf(tmin[qi], t);
    }
  }
  // 16-lane group mins -> 16 disjoint groups; tau = max of group mins
#pragma unroll
  for (int qi = 0; qi < KQ; ++qi) {
    float v = tmin[qi];
    v = fminf(v, __shfl_xor(v, 1));
    v = fminf(v, __shfl_xor(v, 2));
    v = fminf(v, __shfl_xor(v, 4));
    v = fminf(v, __shfl_xor(v, 8));
    if ((tid & 15) == 0) gmin[qi][tid >> 4] = v;
  }
  __syncthreads();
  if (tid < KQ) {
    float t = gmin[tid][0];
#pragma unroll
    for (int g = 1; g < 16; ++g) t = fmaxf(t, gmin[tid][g]);
    tau_s[tid] = t + fabsf(t) * 1e-5f + 1e-6f;   // paranoia margin
  }
  __syncthreads();
  float tau[KQ];
#pragma unroll
  for (int qi = 0; qi < KQ; ++qi) tau[qi] = tau_s[qi];

  // ---- pass 2: collect survivors (exact fp32 d2 stored for arbitration) ----
  {
    float4 cur = pos4[tid];
    for (int it = 0; it < iters; ++it) {
      float4 nxt = cur;
      if (it + 1 < iters) nxt = pos4[tid + (it + 1) * KNN_T];
      const int j = tid + it * KNN_T;
#pragma unroll
      for (int qi = 0; qi < KQ; ++qi) {
        float dot = fmaf(qx[qi], cur.x, fmaf(qy[qi], cur.y, qz[qi] * cur.z));
        float t   = fmaf(-2.0f, dot, cur.w);
        if (t <= tau[qi]) {
          float qq = fmaf(qx[qi], qx[qi],
                          fmaf(qy[qi], qy[qi], qz[qi] * qz[qi]));
          float d2 = fmaxf(qq + t, 0.0f);
          unsigned long long pk =
              ((unsigned long long)__float_as_uint(d2) << 32) | (uint32_t)j;
          int sl = atomicAdd(&cnt[qi], 1);
          if (sl < CAP) cand[qi][sl] = pk;
        }
      }
      cur = nxt;
    }
  }
  __syncthreads();

  // ---- pass 3: one wave per query extracts 16 smallest ----
  const int wv = tid >> 6, ln = tid & 63;
  for (int qi = wv; qi < KQ; qi += 4) {
    int m = q0 + qi;
    unsigned long long c[CAP / 64];
#pragma unroll
    for (int i = 0; i < CAP / 64; ++i) c[i] = cand[qi][i * 64 + ln];
#pragma unroll
    for (int r = 0; r < KNB; ++r) {
      unsigned long long mn = c[0];
#pragma unroll
      for (int i = 1; i < CAP / 64; ++i) mn = (c[i] < mn) ? c[i] : mn;
#pragma unroll
      for (int off = 1; off < 64; off <<= 1) {
        unsigned long long o = __shfl_xor(mn, off);
        mn = (o < mn) ? o : mn;
      }
      if (m < M && ln == 0) nbr[m * KNB + r] = (int)(uint32_t)mn;
#pragma unroll
      for (int i = 0; i < CAP / 64; ++i)
        if (c[i] == mn) c[i] = ~0ull;
    }
  }
}

// ---------------------------------------------------------------------------
// Kernel 2: per-query LocSE + bf16-MFMA attention matvec + softmax + mean.
// 1 wave per query. C-layout: col=lane&15, row=quad*4+reg (verified m89/m91).
// ---------------------------------------------------------------------------
__global__ __launch_bounds__(64) void mid_kernel(
    const float* __restrict__ x, const float4* __restrict__ pos4,
    const int* __restrict__ idx, const float* __restrict__ W_pos,
    const float* __restrict__ b_pos, const unsigned short* __restrict__ Wt,
    const float* __restrict__ b_att, const int* __restrict__ nbr,
    float* __restrict__ aggr, int M) {
  __shared__ float fijf[16][132];                        // +4 pad
  __shared__ __align__(16) unsigned short fijb[16][136]; // +8 pad
  __shared__ int nbr_s[16];

  const int lane = threadIdx.x;
  const int mq   = blockIdx.x;

  if (lane < 16) nbr_s[lane] = nbr[mq * 16 + lane];
  __syncthreads();

  float wp[10];
#pragma unroll
  for (int t = 0; t < 10; ++t) wp[t] = W_pos[t * 64 + lane];
  float bp = b_pos[lane];
  int iq = idx[mq];
  float4 qp = pos4[iq];
  float qx = qp.x, qy = qp.y, qz = qp.z;

#pragma unroll 4
  for (int k = 0; k < 16; ++k) {
    int jn = nbr_s[k];
    float4 pj = pos4[jn];
    float vx = qx - pj.x, vy = qy - pj.y, vz = qz - pj.z;
    float dd = sqrtf(vx * vx + vy * vy + vz * vz);
    float r = bp;
    r += qx * wp[0] + qy * wp[1] + qz * wp[2];
    r += pj.x * wp[3] + pj.y * wp[4] + pj.z * wp[5];
    r += vx * wp[6] + vy * wp[7] + vz * wp[8];
    r += dd * wp[9];
    r = fmaxf(r, 0.0f);
    float xv = x[jn * 64 + lane];
    fijf[k][lane]      = xv;
    fijf[k][64 + lane] = r;
    fijb[k][lane]      = f2bf(xv);
    fijb[k][64 + lane] = f2bf(r);
  }
  __syncthreads();

  const int col = lane & 15, quad = lane >> 4;

  // A-frags: A[m=lane&15][c = cs*32 + quad*8 + j]
  short8 af[4];
#pragma unroll
  for (int cs = 0; cs < 4; ++cs)
    af[cs] = *(const short8*)&fijb[col][cs * 32 + quad * 8];

  floatx4 acc[8];
#pragma unroll
  for (int ft = 0; ft < 8; ++ft) {
    float bav = b_att[ft * 16 + col];
    floatx4 a; a[0] = bav; a[1] = bav; a[2] = bav; a[3] = bav;
#pragma unroll
    for (int cs = 0; cs < 4; ++cs) {
      short8 bfrag = *(const short8*)&Wt[(ft * 16 + col) * 128 + cs * 32 + quad * 8];
      a = __builtin_amdgcn_mfma_f32_16x16x32_bf16(af[cs], bfrag, a, 0, 0, 0);
    }
    acc[ft] = a;
  }

  // softmax over the 128 features per row (row = neighbor)
  float e[8][4], rowsum[4];
#pragma unroll
  for (int r = 0; r < 4; ++r) {
    float mx = acc[0][r];
#pragma unroll
    for (int ft = 1; ft < 8; ++ft) mx = fmaxf(mx, acc[ft][r]);
    mx = fmaxf(mx, __shfl_xor(mx, 1));
    mx = fmaxf(mx, __shfl_xor(mx, 2));
    mx = fmaxf(mx, __shfl_xor(mx, 4));
    mx = fmaxf(mx, __shfl_xor(mx, 8));
    float sm = 0.0f;
#pragma unroll
    for (int ft = 0; ft < 8; ++ft) {
      e[ft][r] = expf(acc[ft][r] - mx);
      sm += e[ft][r];
    }
    sm += __shfl_xor(sm, 1);
    sm += __shfl_xor(sm, 2);
    sm += __shfl_xor(sm, 4);
    sm += __shfl_xor(sm, 8);
    rowsum[r] = sm;
  }

#pragma unroll
  for (int ft = 0; ft < 8; ++ft) {
    float ap = 0.0f;
#pragma unroll
    for (int r = 0; r < 4; ++r) {
      float s = e[ft][r] / rowsum[r];
      ap += s * fijf[quad * 4 + r][ft * 16 + col];
    }
    ap += __shfl_xor(ap, 16);
    ap += __shfl_xor(ap, 32);
    if (quad == 0) aggr[mq * 128 + ft * 16 + col] = ap * (1.0f / 16.0f);
  }
}

// ---------------------------------------------------------------------------
// Kernel 3: out = relu(aggr @ W_glob + b_glob), f32 vector GEMM
// ---------------------------------------------------------------------------
__global__ __launch_bounds__(256) void out_kernel(
    const float* __restrict__ aggr, const float* __restrict__ W_glob,
    const float* __restrict__ b_glob, float* __restrict__ out, int M) {
  __shared__ float ag[16][128];
  const int tid   = threadIdx.x;
  const int mbase = blockIdx.x * 16;
  for (int s = tid; s < 16 * 128; s += 256) {
    int r = s >> 7, cc = s & 127;
    int m = mbase + r;
    ((float*)ag)[s] = (m < M) ? aggr[m * 128 + cc] : 0.0f;
  }
  __syncthreads();
  const int f = tid & 127, h = tid >> 7;
  float acc[8];
  float bg = b_glob[f];
#pragma unroll
  for (int i = 0; i < 8; ++i) acc[i] = bg;
  for (int c = 0; c < 128; c += 4) {
    float w0 = W_glob[(c + 0) * 128 + f];
    float w1 = W_glob[(c + 1) * 128 + f];
    float w2 = W_glob[(c + 2) * 128 + f];
    float w3 = W_glob[(c + 3) * 128 + f];
#pragma unroll
    for (int i = 0; i < 8; ++i) {
      const floatx4 a4 = *(const floatx4*)&ag[h * 8 + i][c];
      acc[i] += a4[0] * w0 + a4[1] * w1 + a4[2] * w2 + a4[3] * w3;
    }
  }
#pragma unroll
  for (int i = 0; i < 8; ++i) {
    int m = mbase + h * 8 + i;
    if (m < M) out[m * 128 + f] = fmaxf(acc[i], 0.0f);
  }
}

// ---------------------------------------------------------------------------
extern "C" void kernel_launch(void* const* d_in, const int* in_sizes, int n_in,
                              void* d_out, int out_size, void* d_ws,
                              size_t ws_size, hipStream_t stream) {
  const float* x      = (const float*)d_in[0];
  const float* pos    = (const float*)d_in[1];
  const int*   idx    = (const int*)d_in[2];
  const float* W_pos  = (const float*)d_in[3];
  const float* b_pos  = (const float*)d_in[4];
  const float* W_att  = (const float*)d_in[5];
  const float* b_att  = (const float*)d_in[6];
  const float* W_glob = (const float*)d_in[7];
  const float* b_glob = (const float*)d_in[8];
  float* out = (float*)d_out;

  const int N    = in_sizes[1] / 3;
  const int M    = in_sizes[2];
  const int Npad = (N + KNN_T - 1) & ~(KNN_T - 1);

  char* ws = (char*)d_ws;
  float4* pos4 = (float4*)ws;                                       // Npad*16B
  size_t off1 = ((size_t)Npad * 16 + 255) & ~(size_t)255;
  int* nbr = (int*)(ws + off1);                                     // M*16 int
  size_t off2 = off1 + (((size_t)M * KNB * 4 + 255) & ~(size_t)255);
  unsigned short* Wt = (unsigned short*)(ws + off2);                // 128*128 bf16
  size_t off3 = off2 + ((128 * 128 * 2 + 255) & ~255);
  float* aggr = (float*)(ws + off3);                                // M*128 f32

  prep_kernel<<<(Npad + 255) / 256, 256, 0, stream>>>(W_att, Wt, pos, pos4, N,
                                                      Npad);
  knn_kernel<<<(M + KQ - 1) / KQ, KNN_T, 0, stream>>>(pos4, idx, nbr, Npad, M);
  mid_kernel<<<M, 64, 0, stream>>>(x, pos4, idx, W_pos, b_pos, Wt, b_att, nbr,
                                   aggr, M);
  out_kernel<<<(M + 15) / 16, 256, 0, stream>>>(aggr, W_glob, b_glob, out, M);
}